// Round 4
// baseline (89.604 us; speedup 1.0000x reference)
//
#include <hip/hip_runtime.h>
#include <math.h>

namespace {
constexpr int   NB   = 25;     // basis functions
constexpr int   TS   = 301;    // time steps
constexpr int   TPAD = 304;    // padded table stride
constexpr float DT   = 0.01f;
constexpr float TAU  = 3.0f;
constexpr float AX   = 2.0f;
constexpr float AZ   = 48.0f;
constexpr float BZ   = 12.0f;  // AZ/4
constexpr int   ROWS = 131072; // BATCH * DOF
}

// ws layout (floats): [0..TPAD) = A_t, [TPAD..2*TPAD) = B_t,
//                     [(2+n)*TPAD + t] = H_t[n]
__global__ __launch_bounds__(512)
void dmp_precompute(const float* __restrict__ c, const float* __restrict__ s2,
                    float* __restrict__ ws) {
  __shared__ float g[TS][NB];
  __shared__ float cS[NB], vS[NB];
  const int tid = threadIdx.x;
  if (tid < NB) { cS[tid] = c[tid]; vS[tid] = s2[tid]; }
  __syncthreads();
  const float q = 1.0f - AX / TAU * DT;   // cx multiplier per step
  for (int i = tid; i < TS; i += 512) {
    float cx = powf(q, (float)(i + 1));   // cx updated BEFORE use in ref
    float p[NB]; float sum = 0.f;
    #pragma unroll
    for (int n = 0; n < NB; ++n) {
      float d = cx - cS[n];
      p[n] = expf(-0.5f * d * d / vS[n]);
      sum += p[n];
    }
    float m = cx / sum;
    #pragma unroll
    for (int n = 0; n < NB; ++n) g[i][n] = p[n] * m;
  }
  __syncthreads();
  // 27 independent linear-response recurrences (lanes 0..26)
  if (tid < NB + 2) {
    float y, gl;
    if (tid == 0)      { y = 1.f; gl = 0.f; }   // response to y0
    else if (tid == 1) { y = 0.f; gl = 1.f; }   // response to goal
    else               { y = 0.f; gl = 0.f; }   // response to unit w_n
    float z = 0.f;
    const int nn = (tid >= 2) ? (tid - 2) : 0;
    float* dst = ws + tid * TPAD;
    for (int t = 0; t < TS; ++t) {
      float fx = (tid >= 2) ? g[t][nn] : 0.f;
      float dy = z / TAU;
      float dz = (AZ * (BZ * (gl - y) - z) + fx) / TAU;
      y += dy * DT;
      z += dz * DT;
      dst[t] = y;
    }
  }
}

// Block = 320 threads = 5 waves (one per 64-t chunk), 64 rows per block.
// Row data (w, y0, goal): all indices uniform (blockIdx + loop counter) ->
// scalar s_load path through K$. Per-lane t-tables (a, b, h0/h1[25]) in
// VGPRs — __launch_bounds__(320,4) raises the VGPR cap to ~128 so the
// compiler keeps them resident (R3 failure: VGPR=32, tables re-loaded).
__global__ __launch_bounds__(320, 4)
void dmp_main(const float* __restrict__ x, const float* __restrict__ scale,
              const float* __restrict__ ws, float* __restrict__ out) {
  const int tid  = threadIdx.x;
  const int lane = tid & 63;
  const int tc   = tid >> 6;          // 0..4
  const int rg   = blockIdx.x;        // row group (64 rows)
  const int t    = tc * 64 + lane;
  const int tl   = (t < TS) ? t : (TS - 1);
  const bool tv  = (t < TS);

  const float a = ws[tl];
  const float b = ws[TPAD + tl];
  float h0[NB], h1[NB];
  #pragma unroll
  for (int k = 0; k < NB; ++k) {
    const float h = ws[(2 + k) * TPAD + tl];
    h0[k] = h * scale[2 + k];          // dof 0
    h1[k] = h * scale[29 + k];         // dof 1
  }
  const float s00 = scale[0],  s01 = scale[1];
  const float s10 = scale[27], s11 = scale[28];

  const int row0 = rg << 6;
  const float* __restrict__ xb = x + (size_t)row0 * 27;

  #pragma unroll 1
  for (int rr = 0; rr < 64; rr += 2) {
    const float* pe = xb + rr * 27;    // even row (dof 0) — uniform addr
    const float* po = pe + 27;         // odd row (dof 1)

    float accA0 = 0.f, accA1 = 0.f, accB0 = 0.f, accB1 = 0.f;
    #pragma unroll
    for (int k = 0; k < 24; k += 2) {
      accA0 = fmaf(pe[2 + k], h0[k],     accA0);
      accA1 = fmaf(pe[3 + k], h0[k + 1], accA1);
      accB0 = fmaf(po[2 + k], h1[k],     accB0);
      accB1 = fmaf(po[3 + k], h1[k + 1], accB1);
    }
    accA0 = fmaf(pe[26], h0[24], accA0);
    accB0 = fmaf(po[26], h1[24], accB0);
    const float accA = accA0 + accA1;
    const float accB = accB0 + accB1;

    const float y0A = pe[0] * s00, gA = pe[1] * s01;
    const float y0B = po[0] * s10, gB = po[1] * s11;
    const float yA = fmaf(a, y0A, b * gA) + (gA - y0A) * accA;
    const float yB = fmaf(a, y0B, b * gB) + (gB - y0B) * accB;
    if (tv) {
      out[(size_t)(row0 + rr) * TS + t]     = yA;
      out[(size_t)(row0 + rr + 1) * TS + t] = yB;
    }
  }
}

extern "C" void kernel_launch(void* const* d_in, const int* in_sizes, int n_in,
                              void* d_out, int out_size, void* d_ws, size_t ws_size,
                              hipStream_t stream) {
  const float* x  = (const float*)d_in[0];
  const float* c  = (const float*)d_in[1];
  const float* s2 = (const float*)d_in[2];
  const float* sc = (const float*)d_in[3];
  float* ws  = (float*)d_ws;   // needs 27*304*4 = 32,832 bytes
  float* out = (float*)d_out;

  hipLaunchKernelGGL(dmp_precompute, dim3(1), dim3(512), 0, stream, c, s2, ws);
  hipLaunchKernelGGL(dmp_main, dim3(ROWS / 64), dim3(320), 0, stream,
                     x, sc, ws, out);
}

// Round 5
// 87.279 us; speedup vs baseline: 1.0266x; 1.0266x over previous
//
#include <hip/hip_runtime.h>
#include <math.h>

namespace {
constexpr int   NB   = 25;     // basis functions
constexpr int   TS   = 301;    // time steps
constexpr int   TPAD = 304;    // padded table stride
constexpr float DT   = 0.01f;
constexpr float TAU  = 3.0f;
constexpr float AX   = 2.0f;
constexpr float AZ   = 48.0f;
constexpr float BZ   = 12.0f;  // AZ/4
constexpr int   ROWS = 131072; // BATCH * DOF
}

// ws layout (floats): [0..TPAD) = A_t, [TPAD..2*TPAD) = B_t,
//                     [(2+n)*TPAD + t] = H_t[n]
__global__ __launch_bounds__(512)
void dmp_precompute(const float* __restrict__ c, const float* __restrict__ s2,
                    float* __restrict__ ws) {
  __shared__ float g[TS][NB];
  __shared__ float cS[NB], vS[NB];
  const int tid = threadIdx.x;
  if (tid < NB) { cS[tid] = c[tid]; vS[tid] = s2[tid]; }
  __syncthreads();
  const float q = 1.0f - AX / TAU * DT;   // cx multiplier per step
  for (int i = tid; i < TS; i += 512) {
    float cx = powf(q, (float)(i + 1));   // cx updated BEFORE use in ref
    float p[NB]; float sum = 0.f;
    #pragma unroll
    for (int n = 0; n < NB; ++n) {
      float d = cx - cS[n];
      p[n] = expf(-0.5f * d * d / vS[n]);
      sum += p[n];
    }
    float m = cx / sum;
    #pragma unroll
    for (int n = 0; n < NB; ++n) g[i][n] = p[n] * m;
  }
  __syncthreads();
  // 27 independent linear-response recurrences (lanes 0..26)
  if (tid < NB + 2) {
    float y, gl;
    if (tid == 0)      { y = 1.f; gl = 0.f; }   // response to y0
    else if (tid == 1) { y = 0.f; gl = 1.f; }   // response to goal
    else               { y = 0.f; gl = 0.f; }   // response to unit w_n
    float z = 0.f;
    const int nn = (tid >= 2) ? (tid - 2) : 0;
    float* dst = ws + tid * TPAD;
    for (int t = 0; t < TS; ++t) {
      float fx = (tid >= 2) ? g[t][nn] : 0.f;
      float dy = z / TAU;
      float dz = (AZ * (BZ * (gl - y) - z) + fx) / TAU;
      y += dy * DT;
      z += dz * DT;
      dst[t] = y;
    }
  }
}

// Block = 320 threads = 5 waves (one per 64-t chunk), 64 rows per block.
// Row data (w, y0, goal): uniform addresses -> scalar s_load path (K$).
// Per-lane t-tables (a, b, h0/h1[25]): loaded once, then PINNED into VGPRs
// via empty asm (R4 failure: compiler sank these loads into the row loop,
// VGPR_Count=32). asm outputs cannot be rematerialized -> stay resident.
__global__ __launch_bounds__(320, 4)
void dmp_main(const float* __restrict__ x, const float* __restrict__ scale,
              const float* __restrict__ ws, float* __restrict__ out) {
  const int tid  = threadIdx.x;
  const int lane = tid & 63;
  const int tc   = tid >> 6;          // 0..4
  const int rg   = blockIdx.x;        // row group (64 rows)
  const int t    = tc * 64 + lane;
  const int tl   = (t < TS) ? t : (TS - 1);
  const bool tv  = (t < TS);

  float a = ws[tl];
  float b = ws[TPAD + tl];
  float h0[NB], h1[NB];
  #pragma unroll
  for (int k = 0; k < NB; ++k) {
    const float h = ws[(2 + k) * TPAD + tl];
    h0[k] = h * scale[2 + k];          // dof 0
    h1[k] = h * scale[29 + k];         // dof 1
  }
  float s00 = scale[0],  s01 = scale[1];
  float s10 = scale[27], s11 = scale[28];

  // Pin all loop-invariant per-lane values into VGPRs.
  asm volatile("" : "+v"(a), "+v"(b), "+v"(s00), "+v"(s01), "+v"(s10), "+v"(s11));
  #pragma unroll
  for (int k = 0; k < NB; ++k) {
    asm volatile("" : "+v"(h0[k]), "+v"(h1[k]));
  }

  const int row0 = rg << 6;
  const float* __restrict__ xb = x + (size_t)row0 * 27;

  #pragma unroll 1
  for (int rr = 0; rr < 64; rr += 2) {
    const float* pe = xb + rr * 27;    // even row (dof 0) — uniform addr
    const float* po = pe + 27;         // odd row (dof 1)

    float accA0 = 0.f, accA1 = 0.f, accB0 = 0.f, accB1 = 0.f;
    #pragma unroll
    for (int k = 0; k < 24; k += 2) {
      accA0 = fmaf(pe[2 + k], h0[k],     accA0);
      accA1 = fmaf(pe[3 + k], h0[k + 1], accA1);
      accB0 = fmaf(po[2 + k], h1[k],     accB0);
      accB1 = fmaf(po[3 + k], h1[k + 1], accB1);
    }
    accA0 = fmaf(pe[26], h0[24], accA0);
    accB0 = fmaf(po[26], h1[24], accB0);
    const float accA = accA0 + accA1;
    const float accB = accB0 + accB1;

    const float y0A = pe[0] * s00, gA = pe[1] * s01;
    const float y0B = po[0] * s10, gB = po[1] * s11;
    const float yA = fmaf(a, y0A, b * gA) + (gA - y0A) * accA;
    const float yB = fmaf(a, y0B, b * gB) + (gB - y0B) * accB;
    if (tv) {
      out[(size_t)(row0 + rr) * TS + t]     = yA;
      out[(size_t)(row0 + rr + 1) * TS + t] = yB;
    }
  }
}

extern "C" void kernel_launch(void* const* d_in, const int* in_sizes, int n_in,
                              void* d_out, int out_size, void* d_ws, size_t ws_size,
                              hipStream_t stream) {
  const float* x  = (const float*)d_in[0];
  const float* c  = (const float*)d_in[1];
  const float* s2 = (const float*)d_in[2];
  const float* sc = (const float*)d_in[3];
  float* ws  = (float*)d_ws;   // needs 27*304*4 = 32,832 bytes
  float* out = (float*)d_out;

  hipLaunchKernelGGL(dmp_precompute, dim3(1), dim3(512), 0, stream, c, s2, ws);
  hipLaunchKernelGGL(dmp_main, dim3(ROWS / 64), dim3(320), 0, stream,
                     x, sc, ws, out);
}